// Round 11
// baseline (296.564 us; speedup 1.0000x reference)
//
#include <hip/hip_runtime.h>
#include <hip/hip_bf16.h>
#include <math.h>

#define B_SIZE 8192
#define D_SIZE 256
#define INV_T 14.285714285714286f
#define LOG2E 1.4426950408889634f
#define LN2 0.6931471805599453f
#define KEY_MASK 0xFFFFE000
#define COL_MASK 0x1FFF

typedef __bf16 bf16x8 __attribute__((ext_vector_type(8)));
typedef float f32x4 __attribute__((ext_vector_type(4)));

__device__ __forceinline__ void gload_lds16(const void* g, void* lds) {
  __builtin_amdgcn_global_load_lds(
      (const __attribute__((address_space(1))) void*)g,
      (__attribute__((address_space(3))) void*)lds, 16, 0, 0);
}

// int compare-exchange: a=max, b=min (v_max_i32 + v_min_i32)
__device__ __forceinline__ void cei(int& a, int& b) {
  const int h = a > b ? a : b;
  const int l = a > b ? b : a;
  a = h; b = l;
}

// merge two sorted-desc int-4 lists, keep top-4 in a
__device__ __forceinline__ void merge_top4i(int a[4], int b[4]) {
  cei(a[0], b[3]); cei(a[1], b[2]); cei(a[2], b[1]); cei(a[3], b[0]);
  cei(a[0], a[2]); cei(a[1], a[3]); cei(a[0], a[1]); cei(a[2], a[3]);
}

// ---------------------------------------------------------------------------
// K0: f32 -> bf16 for BOTH tensors; V side pre-scaled by INV_T*log2e.
// Blocks 0-15 zero row_sum/col_sum; block 0 zeros the done-counter.
// ---------------------------------------------------------------------------
__global__ __launch_bounds__(256) void cvt_both(
    const float* __restrict__ V, const float* __restrict__ T,
    __hip_bfloat16* __restrict__ Vb, __hip_bfloat16* __restrict__ Tb,
    float* __restrict__ sums, unsigned* __restrict__ counter) {
  const int b = blockIdx.x;
  if (b < 16)
    reinterpret_cast<float4*>(sums)[b * 256 + threadIdx.x] =
        float4{0.f, 0.f, 0.f, 0.f};
  if (b == 0 && threadIdx.x == 0) *counter = 0;
  const int half = b >> 11;                       // 0: V, 1: T
  const int i = (b & 2047) * 256 + threadIdx.x;   // 2048*256 = n4 per tensor
  const float sc = half ? 1.0f : (INV_T * LOG2E);
  const float* src = half ? T : V;
  __hip_bfloat16* dst = half ? Tb : Vb;
  const float4 v = reinterpret_cast<const float4*>(src)[i];
  union { __hip_bfloat16 h[4]; short4 s; } u;
  u.h[0] = __float2bfloat16(v.x * sc);
  u.h[1] = __float2bfloat16(v.y * sc);
  u.h[2] = __float2bfloat16(v.z * sc);
  u.h[3] = __float2bfloat16(v.w * sc);
  reinterpret_cast<short4*>(dst)[i] = u.s;
}

// ---------------------------------------------------------------------------
// K1: fused GEMM + register-side analysis (r7 4-wave structure) with a
// 2-phase double-buffered staging pipeline: STAGE(k0+1) issued BEFORE
// compute(k0); one barrier per k0 (its implicit vmcnt(0) drain finds the
// loads already landed, latency hidden under ds_read+MFMA).
// ---------------------------------------------------------------------------
__global__ __launch_bounds__(256) void gemm_analyze(
    const __hip_bfloat16* __restrict__ Vb, const __hip_bfloat16* __restrict__ Tb,
    float* __restrict__ row_sum, float* __restrict__ col_sum,
    float* __restrict__ diag, int* __restrict__ cand_key) {
  // buf b: As at b*32768, Bs at b*32768+16384 (each [128][64] bf16, 16 KB).
  // candK [128][17] ints (8704 B) aliases buf0 after the k-loop.
  __shared__ __align__(16) char smem[65536];
  __shared__ float rsum[128];
  __shared__ float csum[128];

  const int tid  = threadIdx.x;
  const int wave = tid >> 6;
  const int lane = tid & 63;
  const int tileRow = blockIdx.x >> 6;
  const int tileCol = blockIdx.x & 63;
  const int wr = wave >> 1;
  const int wc = wave & 1;
  const int g = lane >> 4;
  const int frow = lane & 15;
  const int rsw = frow & 7;          // read-side swizzle key

  if (tid < 128) rsum[tid] = 0.f; else csum[tid - 128] = 0.f;

  f32x4 acc[4][4];
#pragma unroll
  for (int m = 0; m < 4; ++m)
#pragma unroll
    for (int n = 0; n < 4; ++n)
      acc[m][n] = f32x4{0.f, 0.f, 0.f, 0.f};

  // staging: linear LDS dest + inverse-swizzled global source (rule 21)
  const int srow = wave * 32 + (lane >> 3);
  const int scol = ((lane & 7) ^ ((lane >> 3) & 7)) * 8;
  const __hip_bfloat16* Ag = Vb + (size_t)(tileRow * 128 + srow) * D_SIZE + scol;
  const __hip_bfloat16* Bg = Tb + (size_t)(tileCol * 128 + srow) * D_SIZE + scol;

  auto STAGE = [&](int buf, int k0) {
    char* aS = smem + buf * 32768 + wave * 4096;
    char* bS = aS + 16384;
#pragma unroll
    for (int i = 0; i < 4; ++i) {
      gload_lds16(Ag + (size_t)i * 8 * D_SIZE + k0, aS + i * 1024);
      gload_lds16(Bg + (size_t)i * 8 * D_SIZE + k0, bS + i * 1024);
    }
  };

  STAGE(0, 0);
  __syncthreads();                    // prologue drain

#pragma unroll
  for (int t = 0; t < 4; ++t) {
    const int cur = t & 1;
    if (t < 3) STAGE(cur ^ 1, (t + 1) * 64);   // prefetch next k0
    const char* aB = smem + cur * 32768;
    const char* bB = aB + 16384;
#pragma unroll
    for (int ks = 0; ks < 64; ks += 32) {
      const int cbase = (ks >> 3) + g;
      const int coff = ((cbase ^ rsw) << 4);
      bf16x8 tf[4], vf[4];
#pragma unroll
      for (int n = 0; n < 4; ++n)
        tf[n] = *reinterpret_cast<const bf16x8*>(
            bB + (wc * 64 + n * 16 + frow) * 128 + coff);
#pragma unroll
      for (int m = 0; m < 4; ++m)
        vf[m] = *reinterpret_cast<const bf16x8*>(
            aB + (wr * 64 + m * 16 + frow) * 128 + coff);
#pragma unroll
      for (int m = 0; m < 4; ++m)
#pragma unroll
        for (int n = 0; n < 4; ++n)
          acc[m][n] = __builtin_amdgcn_mfma_f32_16x16x32_bf16(
              tf[n], vf[m], acc[m][n], 0, 0, 0);
    }
    __syncthreads();   // drains next-k0 loads (latency already covered)
  }

  // -------- register-side analysis (acc = sim/T * log2e) --------
  int* candK = reinterpret_cast<int*>(smem);    // [128][17]

  const bool diagT = (tileRow == tileCol) && (wr == wc);
  const bool diagLane = diagT && (g == (frow >> 2));
  const int rowBase = tileRow * 128 + wr * 64;
  const int colOr = tileCol * 128 + wc * 64 + g * 4;  // low-13-bit index base

  float cp[16];
#pragma unroll
  for (int k = 0; k < 16; ++k) cp[k] = 0.f;

#pragma unroll
  for (int m = 0; m < 4; ++m) {
    float rs = 0.f;
    int t0 = (int)0x80000000, t1 = (int)0x80000000;
#pragma unroll
    for (int n = 0; n < 4; ++n) {
#pragma unroll
      for (int r = 0; r < 4; ++r) {
        const float a = acc[m][n][r];
        const float e = exp2f(a);
        rs += e;
        cp[n * 4 + r] += e;
        const int key =
            ((__float_as_int(a) & KEY_MASK) | colOr) | (n * 16 + r);
        t1 = max(t1, min(t0, key));
        t0 = max(t0, key);
      }
    }
    rs += __shfl_xor(rs, 16);
    rs += __shfl_xor(rs, 32);
    if (g == 0) atomicAdd(&rsum[wr * 64 + m * 16 + frow], rs);
    if (diagLane) {
      // diag (logit ~20.6 log2) is guaranteed t0 of this lane: drop it.
      const int rr = frow & 3;
      float dv = acc[m][m][0];
      dv = rr == 1 ? acc[m][m][1] : dv;
      dv = rr == 2 ? acc[m][m][2] : dv;
      dv = rr == 3 ? acc[m][m][3] : dv;
      diag[rowBase + m * 16 + frow] = dv * LN2;   // back to nats
      t0 = t1; t1 = (int)0x80000000;
    }
    const int cb = (wr * 64 + m * 16 + frow) * 17 + (wc * 4 + g) * 2;
    candK[cb] = t0; candK[cb + 1] = t1;
  }

  // col sums: transpose-reduce cp[16] across the 16-lane group
#pragma unroll
  for (int s = 8; s >= 1; s >>= 1) {
    const bool up = (lane & s) != 0;
#pragma unroll
    for (int k = 0; k < 8; ++k) {
      if (k < s) {
        const float send = up ? cp[k] : cp[k + s];
        const float recv = __shfl_xor(send, s);
        cp[k] = (up ? cp[k + s] : cp[k]) + recv;
      }
    }
  }
  atomicAdd(&csum[wc * 64 + ((frow >> 2) << 4) + (g << 2) + (frow & 3)], cp[0]);

  __syncthreads();

  // -------- per-row merge of 8 sorted-2 key lists + global writes --------
  if (tid < 128) {
    const int row = tid;
    const int base = row * 17;
    int a[4] = {candK[base], candK[base + 1], (int)0x80000000, (int)0x80000000};
#pragma unroll
    for (int l = 1; l < 8; ++l) {
      int b[4] = {candK[base + l * 2], candK[base + l * 2 + 1],
                  (int)0x80000000, (int)0x80000000};
      merge_top4i(a, b);
    }
    const int gRow = tileRow * 128 + row;
    const size_t cb = ((size_t)gRow << 8) + (tileCol << 2);
    int4 o; o.x = a[0]; o.y = a[1]; o.z = a[2]; o.w = a[3];
    *reinterpret_cast<int4*>(cand_key + cb) = o;
    atomicAdd(&row_sum[gRow], rsum[row]);
  } else {
    const int c = tid - 128;
    atomicAdd(&col_sum[tileCol * 128 + c], csum[c]);
  }
}

// ---------------------------------------------------------------------------
// K2: merge per-tile top-4 keys -> global top-4 per row; apply alpha
// corrections; LAST block (atomic counter) computes the final loss
// (fused finalize — saves one dispatch).
// ---------------------------------------------------------------------------
__global__ __launch_bounds__(256) void merge_finalize(
    const int* __restrict__ cand_key,
    float* __restrict__ row_sum, float* __restrict__ col_sum,
    const float* __restrict__ diag, unsigned* __restrict__ counter,
    float* __restrict__ out) {
  const int wave = threadIdx.x >> 6;
  const int lane = threadIdx.x & 63;
  const int row = blockIdx.x * 4 + wave;

  const int4 k4 = *reinterpret_cast<const int4*>(
      cand_key + ((size_t)row << 8) + lane * 4);
  int v[4] = {k4.x, k4.y, k4.z, k4.w};

#pragma unroll
  for (int s = 1; s < 64; s <<= 1) {
    int b[4];
#pragma unroll
    for (int k = 0; k < 4; ++k) b[k] = __shfl_xor(v[k], s);
    merge_top4i(v, b);
  }

  if (lane == 0) {
    float corr = 0.f;
#pragma unroll
    for (int k = 0; k < 4; ++k) {
      const float a = __int_as_float(v[k] & KEY_MASK);
      const float c = exp2f(a + a) - exp2f(a);
      corr += c;
      atomicAdd(&col_sum[v[k] & COL_MASK], c);
    }
    row_sum[row] += corr;   // exclusive owner
    __threadfence();        // release this block's writes device-wide
  }
  __syncthreads();

  __shared__ unsigned lastFlag;
  if (threadIdx.x == 0)
    lastFlag = (atomicAdd(counter, 1u) == gridDim.x - 1) ? 1u : 0u;
  __syncthreads();
  if (!lastFlag) return;
  __threadfence();          // acquire: see all other blocks' writes

  double s = 0.0;
  for (int i = threadIdx.x; i < B_SIZE; i += 256)
    s += (double)(logf(row_sum[i]) + logf(col_sum[i]) - 2.f * diag[i]);
#pragma unroll
  for (int d = 1; d < 64; d <<= 1) s += __shfl_xor(s, d);
  __shared__ double red[4];
  if (lane == 0) red[wave] = s;
  __syncthreads();
  if (threadIdx.x == 0) {
    const double tot = red[0] + red[1] + red[2] + red[3];
    out[0] = (float)(tot / (2.0 * (double)B_SIZE));
  }
}

// ---------------------------------------------------------------------------
extern "C" void kernel_launch(void* const* d_in, const int* in_sizes, int n_in,
                              void* d_out, int out_size, void* d_ws, size_t ws_size,
                              hipStream_t stream) {
  const float* V = (const float*)d_in[0];
  const float* T = (const float*)d_in[1];
  float* out = (float*)d_out;
  char* ws = (char*)d_ws;

  __hip_bfloat16* Vb = (__hip_bfloat16*)ws;                       // 4 MB
  __hip_bfloat16* Tb = (__hip_bfloat16*)(ws + (4 << 20));         // 4 MB
  float* row_sum = (float*)(ws + (8 << 20));                      // 32 KB
  float* col_sum = row_sum + B_SIZE;                              // 32 KB
  float* diag    = col_sum + B_SIZE;                              // 32 KB
  int*   cand_key = (int*)(ws + (8 << 20) + 3 * B_SIZE * 4);      // 8 MB
  unsigned* counter = (unsigned*)((char*)cand_key + (8 << 20));   // 4 B

  cvt_both<<<4096, 256, 0, stream>>>(V, T, Vb, Tb, row_sum, counter);
  gemm_analyze<<<64 * 64, 256, 0, stream>>>(Vb, Tb, row_sum, col_sum, diag,
                                            cand_key);
  merge_finalize<<<B_SIZE / 4, 256, 0, stream>>>(cand_key, row_sum, col_sum,
                                                 diag, counter, out);
}

// Round 12
// 170.688 us; speedup vs baseline: 1.7375x; 1.7375x over previous
//
#include <hip/hip_runtime.h>
#include <hip/hip_bf16.h>
#include <math.h>

#define B_SIZE 8192
#define D_SIZE 256
#define INV_T 14.285714285714286f
#define LOG2E 1.4426950408889634f
#define LN2 0.6931471805599453f
#define KEY_MASK 0xFFFFE000
#define COL_MASK 0x1FFF

typedef __bf16 bf16x8 __attribute__((ext_vector_type(8)));
typedef float f32x4 __attribute__((ext_vector_type(4)));

__device__ __forceinline__ void gload_lds16(const void* g, void* lds) {
  __builtin_amdgcn_global_load_lds(
      (const __attribute__((address_space(1))) void*)g,
      (__attribute__((address_space(3))) void*)lds, 16, 0, 0);
}

// int compare-exchange: a=max, b=min (v_max_i32 + v_min_i32)
__device__ __forceinline__ void cei(int& a, int& b) {
  const int h = a > b ? a : b;
  const int l = a > b ? b : a;
  a = h; b = l;
}

// merge two sorted-desc int-4 lists, keep top-4 in a
__device__ __forceinline__ void merge_top4i(int a[4], int b[4]) {
  cei(a[0], b[3]); cei(a[1], b[2]); cei(a[2], b[1]); cei(a[3], b[0]);
  cei(a[0], a[2]); cei(a[1], a[3]); cei(a[0], a[1]); cei(a[2], a[3]);
}

// ---------------------------------------------------------------------------
// K0: f32 -> bf16 for BOTH tensors; V side pre-scaled by INV_T*log2e.
// Blocks 0-15 zero row_sum/col_sum.
// ---------------------------------------------------------------------------
__global__ __launch_bounds__(256) void cvt_both(
    const float* __restrict__ V, const float* __restrict__ T,
    __hip_bfloat16* __restrict__ Vb, __hip_bfloat16* __restrict__ Tb,
    float* __restrict__ sums) {
  const int b = blockIdx.x;
  if (b < 16)
    reinterpret_cast<float4*>(sums)[b * 256 + threadIdx.x] =
        float4{0.f, 0.f, 0.f, 0.f};
  const int half = b >> 11;                       // 0: V, 1: T
  const int i = (b & 2047) * 256 + threadIdx.x;   // 2048*256 = n4 per tensor
  const float sc = half ? 1.0f : (INV_T * LOG2E);
  const float* src = half ? T : V;
  __hip_bfloat16* dst = half ? Tb : Vb;
  const float4 v = reinterpret_cast<const float4*>(src)[i];
  union { __hip_bfloat16 h[4]; short4 s; } u;
  u.h[0] = __float2bfloat16(v.x * sc);
  u.h[1] = __float2bfloat16(v.y * sc);
  u.h[2] = __float2bfloat16(v.z * sc);
  u.h[3] = __float2bfloat16(v.w * sc);
  reinterpret_cast<short4*>(dst)[i] = u.s;
}

// ---------------------------------------------------------------------------
// K1: fused GEMM + register-side analysis (4-wave, 128x128 tile) with a
// 2-phase double-buffered staging pipeline: STAGE(k0+1) issued BEFORE
// compute(k0); one barrier per k0 (its implicit vmcnt(0) drain finds the
// loads already landed, latency hidden under ds_read+MFMA).
// ---------------------------------------------------------------------------
__global__ __launch_bounds__(256) void gemm_analyze(
    const __hip_bfloat16* __restrict__ Vb, const __hip_bfloat16* __restrict__ Tb,
    float* __restrict__ row_sum, float* __restrict__ col_sum,
    float* __restrict__ diag, int* __restrict__ cand_key) {
  // buf b: As at b*32768, Bs at b*32768+16384 (each [128][64] bf16, 16 KB).
  // candK [128][17] ints (8704 B) aliases buf0 after the k-loop.
  __shared__ __align__(16) char smem[65536];
  __shared__ float rsum[128];
  __shared__ float csum[128];

  const int tid  = threadIdx.x;
  const int wave = tid >> 6;
  const int lane = tid & 63;
  const int tileRow = blockIdx.x >> 6;
  const int tileCol = blockIdx.x & 63;
  const int wr = wave >> 1;
  const int wc = wave & 1;
  const int g = lane >> 4;
  const int frow = lane & 15;
  const int rsw = frow & 7;          // read-side swizzle key

  if (tid < 128) rsum[tid] = 0.f; else csum[tid - 128] = 0.f;

  f32x4 acc[4][4];
#pragma unroll
  for (int m = 0; m < 4; ++m)
#pragma unroll
    for (int n = 0; n < 4; ++n)
      acc[m][n] = f32x4{0.f, 0.f, 0.f, 0.f};

  // staging: linear LDS dest + inverse-swizzled global source (rule 21)
  const int srow = wave * 32 + (lane >> 3);
  const int scol = ((lane & 7) ^ ((lane >> 3) & 7)) * 8;
  const __hip_bfloat16* Ag = Vb + (size_t)(tileRow * 128 + srow) * D_SIZE + scol;
  const __hip_bfloat16* Bg = Tb + (size_t)(tileCol * 128 + srow) * D_SIZE + scol;

  auto STAGE = [&](int buf, int k0) {
    char* aS = smem + buf * 32768 + wave * 4096;
    char* bS = aS + 16384;
#pragma unroll
    for (int i = 0; i < 4; ++i) {
      gload_lds16(Ag + (size_t)i * 8 * D_SIZE + k0, aS + i * 1024);
      gload_lds16(Bg + (size_t)i * 8 * D_SIZE + k0, bS + i * 1024);
    }
  };

  STAGE(0, 0);
  __syncthreads();                    // prologue drain

#pragma unroll
  for (int t = 0; t < 4; ++t) {
    const int cur = t & 1;
    if (t < 3) STAGE(cur ^ 1, (t + 1) * 64);   // prefetch next k0
    const char* aB = smem + cur * 32768;
    const char* bB = aB + 16384;
#pragma unroll
    for (int ks = 0; ks < 64; ks += 32) {
      const int cbase = (ks >> 3) + g;
      const int coff = ((cbase ^ rsw) << 4);
      bf16x8 tf[4], vf[4];
#pragma unroll
      for (int n = 0; n < 4; ++n)
        tf[n] = *reinterpret_cast<const bf16x8*>(
            bB + (wc * 64 + n * 16 + frow) * 128 + coff);
#pragma unroll
      for (int m = 0; m < 4; ++m)
        vf[m] = *reinterpret_cast<const bf16x8*>(
            aB + (wr * 64 + m * 16 + frow) * 128 + coff);
#pragma unroll
      for (int m = 0; m < 4; ++m)
#pragma unroll
        for (int n = 0; n < 4; ++n)
          acc[m][n] = __builtin_amdgcn_mfma_f32_16x16x32_bf16(
              tf[n], vf[m], acc[m][n], 0, 0, 0);
    }
    __syncthreads();   // drains next-k0 loads (latency already covered)
  }

  // -------- register-side analysis (acc = sim/T * log2e) --------
  int* candK = reinterpret_cast<int*>(smem);    // [128][17]

  const bool diagT = (tileRow == tileCol) && (wr == wc);
  const bool diagLane = diagT && (g == (frow >> 2));
  const int rowBase = tileRow * 128 + wr * 64;
  const int colOr = tileCol * 128 + wc * 64 + g * 4;  // low-13-bit index base

  float cp[16];
#pragma unroll
  for (int k = 0; k < 16; ++k) cp[k] = 0.f;

#pragma unroll
  for (int m = 0; m < 4; ++m) {
    float rs = 0.f;
    int t0 = (int)0x80000000, t1 = (int)0x80000000;
#pragma unroll
    for (int n = 0; n < 4; ++n) {
#pragma unroll
      for (int r = 0; r < 4; ++r) {
        const float a = acc[m][n][r];
        const float e = exp2f(a);
        rs += e;
        cp[n * 4 + r] += e;
        const int key =
            ((__float_as_int(a) & KEY_MASK) | colOr) | (n * 16 + r);
        t1 = max(t1, min(t0, key));
        t0 = max(t0, key);
      }
    }
    rs += __shfl_xor(rs, 16);
    rs += __shfl_xor(rs, 32);
    if (g == 0) atomicAdd(&rsum[wr * 64 + m * 16 + frow], rs);
    if (diagLane) {
      // diag (logit ~20.6 log2) is guaranteed t0 of this lane: drop it.
      const int rr = frow & 3;
      float dv = acc[m][m][0];
      dv = rr == 1 ? acc[m][m][1] : dv;
      dv = rr == 2 ? acc[m][m][2] : dv;
      dv = rr == 3 ? acc[m][m][3] : dv;
      diag[rowBase + m * 16 + frow] = dv * LN2;   // back to nats
      t0 = t1; t1 = (int)0x80000000;
    }
    const int cb = (wr * 64 + m * 16 + frow) * 17 + (wc * 4 + g) * 2;
    candK[cb] = t0; candK[cb + 1] = t1;
  }

  // col sums: transpose-reduce cp[16] across the 16-lane group
#pragma unroll
  for (int s = 8; s >= 1; s >>= 1) {
    const bool up = (lane & s) != 0;
#pragma unroll
    for (int k = 0; k < 8; ++k) {
      if (k < s) {
        const float send = up ? cp[k] : cp[k + s];
        const float recv = __shfl_xor(send, s);
        cp[k] = (up ? cp[k + s] : cp[k]) + recv;
      }
    }
  }
  atomicAdd(&csum[wc * 64 + ((frow >> 2) << 4) + (g << 2) + (frow & 3)], cp[0]);

  __syncthreads();

  // -------- per-row merge of 8 sorted-2 key lists + global writes --------
  if (tid < 128) {
    const int row = tid;
    const int base = row * 17;
    int a[4] = {candK[base], candK[base + 1], (int)0x80000000, (int)0x80000000};
#pragma unroll
    for (int l = 1; l < 8; ++l) {
      int b[4] = {candK[base + l * 2], candK[base + l * 2 + 1],
                  (int)0x80000000, (int)0x80000000};
      merge_top4i(a, b);
    }
    const int gRow = tileRow * 128 + row;
    const size_t cb = ((size_t)gRow << 8) + (tileCol << 2);
    int4 o; o.x = a[0]; o.y = a[1]; o.z = a[2]; o.w = a[3];
    *reinterpret_cast<int4*>(cand_key + cb) = o;
    atomicAdd(&row_sum[gRow], rsum[row]);
  } else {
    const int c = tid - 128;
    atomicAdd(&col_sum[tileCol * 128 + c], csum[c]);
  }
}

// ---------------------------------------------------------------------------
// K2: merge 64 per-tile sorted-4 key lists -> global top-4 per row; apply
// alpha corrections (2^{2a} - 2^a) to row_sum (owned) and col_sum (atomic).
// (Separate dispatch from finalize: kernel-boundary coherence is free;
// fused last-block + __threadfence cost 143 us in r11 — never again.)
// ---------------------------------------------------------------------------
__global__ __launch_bounds__(256) void merge_correct(
    const int* __restrict__ cand_key,
    float* __restrict__ row_sum, float* __restrict__ col_sum) {
  const int wave = threadIdx.x >> 6;
  const int lane = threadIdx.x & 63;
  const int row = blockIdx.x * 4 + wave;

  const int4 k4 = *reinterpret_cast<const int4*>(
      cand_key + ((size_t)row << 8) + lane * 4);
  int v[4] = {k4.x, k4.y, k4.z, k4.w};

#pragma unroll
  for (int s = 1; s < 64; s <<= 1) {
    int b[4];
#pragma unroll
    for (int k = 0; k < 4; ++k) b[k] = __shfl_xor(v[k], s);
    merge_top4i(v, b);
  }

  if (lane == 0) {
    float corr = 0.f;
#pragma unroll
    for (int k = 0; k < 4; ++k) {
      const float a = __int_as_float(v[k] & KEY_MASK);
      const float c = exp2f(a + a) - exp2f(a);
      corr += c;
      atomicAdd(&col_sum[v[k] & COL_MASK], c);
    }
    row_sum[row] += corr;   // exclusive owner after K1 completes
  }
}

// ---------------------------------------------------------------------------
// K3: final loss reduction
// ---------------------------------------------------------------------------
__global__ __launch_bounds__(256) void finalize(
    const float* __restrict__ row_sum, const float* __restrict__ col_sum,
    const float* __restrict__ diag, float* __restrict__ out) {
  double s = 0.0;
  for (int i = threadIdx.x; i < B_SIZE; i += 256)
    s += (double)(logf(row_sum[i]) + logf(col_sum[i]) - 2.f * diag[i]);
#pragma unroll
  for (int d = 1; d < 64; d <<= 1) s += __shfl_xor(s, d);
  __shared__ double red[4];
  const int lane = threadIdx.x & 63, wave = threadIdx.x >> 6;
  if (lane == 0) red[wave] = s;
  __syncthreads();
  if (threadIdx.x == 0) {
    const double tot = red[0] + red[1] + red[2] + red[3];
    out[0] = (float)(tot / (2.0 * (double)B_SIZE));
  }
}

// ---------------------------------------------------------------------------
extern "C" void kernel_launch(void* const* d_in, const int* in_sizes, int n_in,
                              void* d_out, int out_size, void* d_ws, size_t ws_size,
                              hipStream_t stream) {
  const float* V = (const float*)d_in[0];
  const float* T = (const float*)d_in[1];
  float* out = (float*)d_out;
  char* ws = (char*)d_ws;

  __hip_bfloat16* Vb = (__hip_bfloat16*)ws;                       // 4 MB
  __hip_bfloat16* Tb = (__hip_bfloat16*)(ws + (4 << 20));         // 4 MB
  float* row_sum = (float*)(ws + (8 << 20));                      // 32 KB
  float* col_sum = row_sum + B_SIZE;                              // 32 KB
  float* diag    = col_sum + B_SIZE;                              // 32 KB
  int*   cand_key = (int*)(ws + (8 << 20) + 3 * B_SIZE * 4);      // 8 MB

  cvt_both<<<4096, 256, 0, stream>>>(V, T, Vb, Tb, row_sum);
  gemm_analyze<<<64 * 64, 256, 0, stream>>>(Vb, Tb, row_sum, col_sum, diag,
                                            cand_key);
  merge_correct<<<B_SIZE / 4, 256, 0, stream>>>(cand_key, row_sum, col_sum);
  finalize<<<1, 256, 0, stream>>>(row_sum, col_sum, diag, out);
}

// Round 13
// 165.456 us; speedup vs baseline: 1.7924x; 1.0316x over previous
//
#include <hip/hip_runtime.h>
#include <hip/hip_bf16.h>
#include <math.h>

#define B_SIZE 8192
#define D_SIZE 256
#define INV_T 14.285714285714286f
#define LOG2E 1.4426950408889634f
#define LN2 0.6931471805599453f
#define KEY_MASK 0xFFFFE000
#define COL_MASK 0x1FFF

typedef __bf16 bf16x8 __attribute__((ext_vector_type(8)));
typedef float f32x4 __attribute__((ext_vector_type(4)));

// bare v_exp_f32 (2^x): libm exp2f routes through __ocml_exp2_f32's range
// fixups (~5-8 insts); our domain |x|<=~30 needs none of that.
extern "C" __device__ __attribute__((const)) float __ocml_native_exp2_f32(float);
#define EXP2(x) __ocml_native_exp2_f32(x)

__device__ __forceinline__ void gload_lds16(const void* g, void* lds) {
  __builtin_amdgcn_global_load_lds(
      (const __attribute__((address_space(1))) void*)g,
      (__attribute__((address_space(3))) void*)lds, 16, 0, 0);
}

// int compare-exchange: a=max, b=min (v_max_i32 + v_min_i32)
__device__ __forceinline__ void cei(int& a, int& b) {
  const int h = a > b ? a : b;
  const int l = a > b ? b : a;
  a = h; b = l;
}

// merge two sorted-desc int-4 lists, keep top-4 in a
__device__ __forceinline__ void merge_top4i(int a[4], int b[4]) {
  cei(a[0], b[3]); cei(a[1], b[2]); cei(a[2], b[1]); cei(a[3], b[0]);
  cei(a[0], a[2]); cei(a[1], a[3]); cei(a[0], a[1]); cei(a[2], a[3]);
}

// ---------------------------------------------------------------------------
// K0: f32 -> bf16 for BOTH tensors; V side pre-scaled by INV_T*log2e.
// Blocks 0-15 zero row_sum/col_sum.
// ---------------------------------------------------------------------------
__global__ __launch_bounds__(256) void cvt_both(
    const float* __restrict__ V, const float* __restrict__ T,
    __hip_bfloat16* __restrict__ Vb, __hip_bfloat16* __restrict__ Tb,
    float* __restrict__ sums) {
  const int b = blockIdx.x;
  if (b < 16)
    reinterpret_cast<float4*>(sums)[b * 256 + threadIdx.x] =
        float4{0.f, 0.f, 0.f, 0.f};
  const int half = b >> 11;                       // 0: V, 1: T
  const int i = (b & 2047) * 256 + threadIdx.x;   // 2048*256 = n4 per tensor
  const float sc = half ? 1.0f : (INV_T * LOG2E);
  const float* src = half ? T : V;
  __hip_bfloat16* dst = half ? Tb : Vb;
  const float4 v = reinterpret_cast<const float4*>(src)[i];
  union { __hip_bfloat16 h[4]; short4 s; } u;
  u.h[0] = __float2bfloat16(v.x * sc);
  u.h[1] = __float2bfloat16(v.y * sc);
  u.h[2] = __float2bfloat16(v.z * sc);
  u.h[3] = __float2bfloat16(v.w * sc);
  reinterpret_cast<short4*>(dst)[i] = u.s;
}

// ---------------------------------------------------------------------------
// K1: fused GEMM + register-side analysis (4-wave, 128x128 tile), 2-phase
// double-buffered staging (measured neutral vs single-buffer, kept).
// Analysis: packed int keys, exp2 domain, NATIVE v_exp_f32.
// ---------------------------------------------------------------------------
__global__ __launch_bounds__(256) void gemm_analyze(
    const __hip_bfloat16* __restrict__ Vb, const __hip_bfloat16* __restrict__ Tb,
    float* __restrict__ row_sum, float* __restrict__ col_sum,
    float* __restrict__ diag, int* __restrict__ cand_key) {
  // buf b: As at b*32768, Bs at b*32768+16384 (each [128][64] bf16, 16 KB).
  // candK [128][17] ints (8704 B) aliases buf0 after the k-loop.
  __shared__ __align__(16) char smem[65536];
  __shared__ float rsum[128];
  __shared__ float csum[128];

  const int tid  = threadIdx.x;
  const int wave = tid >> 6;
  const int lane = tid & 63;
  const int tileRow = blockIdx.x >> 6;
  const int tileCol = blockIdx.x & 63;
  const int wr = wave >> 1;
  const int wc = wave & 1;
  const int g = lane >> 4;
  const int frow = lane & 15;
  const int rsw = frow & 7;          // read-side swizzle key

  if (tid < 128) rsum[tid] = 0.f; else csum[tid - 128] = 0.f;

  f32x4 acc[4][4];
#pragma unroll
  for (int m = 0; m < 4; ++m)
#pragma unroll
    for (int n = 0; n < 4; ++n)
      acc[m][n] = f32x4{0.f, 0.f, 0.f, 0.f};

  // staging: linear LDS dest + inverse-swizzled global source (rule 21)
  const int srow = wave * 32 + (lane >> 3);
  const int scol = ((lane & 7) ^ ((lane >> 3) & 7)) * 8;
  const __hip_bfloat16* Ag = Vb + (size_t)(tileRow * 128 + srow) * D_SIZE + scol;
  const __hip_bfloat16* Bg = Tb + (size_t)(tileCol * 128 + srow) * D_SIZE + scol;

  auto STAGE = [&](int buf, int k0) {
    char* aS = smem + buf * 32768 + wave * 4096;
    char* bS = aS + 16384;
#pragma unroll
    for (int i = 0; i < 4; ++i) {
      gload_lds16(Ag + (size_t)i * 8 * D_SIZE + k0, aS + i * 1024);
      gload_lds16(Bg + (size_t)i * 8 * D_SIZE + k0, bS + i * 1024);
    }
  };

  STAGE(0, 0);
  __syncthreads();                    // prologue drain

#pragma unroll
  for (int t = 0; t < 4; ++t) {
    const int cur = t & 1;
    if (t < 3) STAGE(cur ^ 1, (t + 1) * 64);   // prefetch next k0
    const char* aB = smem + cur * 32768;
    const char* bB = aB + 16384;
#pragma unroll
    for (int ks = 0; ks < 64; ks += 32) {
      const int cbase = (ks >> 3) + g;
      const int coff = ((cbase ^ rsw) << 4);
      bf16x8 tf[4], vf[4];
#pragma unroll
      for (int n = 0; n < 4; ++n)
        tf[n] = *reinterpret_cast<const bf16x8*>(
            bB + (wc * 64 + n * 16 + frow) * 128 + coff);
#pragma unroll
      for (int m = 0; m < 4; ++m)
        vf[m] = *reinterpret_cast<const bf16x8*>(
            aB + (wr * 64 + m * 16 + frow) * 128 + coff);
#pragma unroll
      for (int m = 0; m < 4; ++m)
#pragma unroll
        for (int n = 0; n < 4; ++n)
          acc[m][n] = __builtin_amdgcn_mfma_f32_16x16x32_bf16(
              tf[n], vf[m], acc[m][n], 0, 0, 0);
    }
    __syncthreads();   // drains next-k0 loads (latency already covered)
  }

  // -------- register-side analysis (acc = sim/T * log2e) --------
  int* candK = reinterpret_cast<int*>(smem);    // [128][17]

  const bool diagT = (tileRow == tileCol) && (wr == wc);
  const bool diagLane = diagT && (g == (frow >> 2));
  const int rowBase = tileRow * 128 + wr * 64;
  const int colOr = tileCol * 128 + wc * 64 + g * 4;  // low-13-bit index base

  float cp[16];
#pragma unroll
  for (int k = 0; k < 16; ++k) cp[k] = 0.f;

#pragma unroll
  for (int m = 0; m < 4; ++m) {
    float rs = 0.f;
    int t0 = (int)0x80000000, t1 = (int)0x80000000;
#pragma unroll
    for (int n = 0; n < 4; ++n) {
#pragma unroll
      for (int r = 0; r < 4; ++r) {
        const float a = acc[m][n][r];
        const float e = EXP2(a);
        rs += e;
        cp[n * 4 + r] += e;
        const int key =
            ((__float_as_int(a) & KEY_MASK) | colOr) | (n * 16 + r);
        t1 = max(t1, min(t0, key));
        t0 = max(t0, key);
      }
    }
    rs += __shfl_xor(rs, 16);
    rs += __shfl_xor(rs, 32);
    if (g == 0) atomicAdd(&rsum[wr * 64 + m * 16 + frow], rs);
    if (diagLane) {
      // diag (logit ~20.6 log2) is guaranteed t0 of this lane: drop it.
      const int rr = frow & 3;
      float dv = acc[m][m][0];
      dv = rr == 1 ? acc[m][m][1] : dv;
      dv = rr == 2 ? acc[m][m][2] : dv;
      dv = rr == 3 ? acc[m][m][3] : dv;
      diag[rowBase + m * 16 + frow] = dv * LN2;   // back to nats
      t0 = t1; t1 = (int)0x80000000;
    }
    const int cb = (wr * 64 + m * 16 + frow) * 17 + (wc * 4 + g) * 2;
    candK[cb] = t0; candK[cb + 1] = t1;
  }

  // col sums: transpose-reduce cp[16] across the 16-lane group
#pragma unroll
  for (int s = 8; s >= 1; s >>= 1) {
    const bool up = (lane & s) != 0;
#pragma unroll
    for (int k = 0; k < 8; ++k) {
      if (k < s) {
        const float send = up ? cp[k] : cp[k + s];
        const float recv = __shfl_xor(send, s);
        cp[k] = (up ? cp[k + s] : cp[k]) + recv;
      }
    }
  }
  atomicAdd(&csum[wc * 64 + ((frow >> 2) << 4) + (g << 2) + (frow & 3)], cp[0]);

  __syncthreads();

  // -------- per-row merge of 8 sorted-2 key lists + global writes --------
  if (tid < 128) {
    const int row = tid;
    const int base = row * 17;
    int a[4] = {candK[base], candK[base + 1], (int)0x80000000, (int)0x80000000};
#pragma unroll
    for (int l = 1; l < 8; ++l) {
      int b[4] = {candK[base + l * 2], candK[base + l * 2 + 1],
                  (int)0x80000000, (int)0x80000000};
      merge_top4i(a, b);
    }
    const int gRow = tileRow * 128 + row;
    const size_t cb = ((size_t)gRow << 8) + (tileCol << 2);
    int4 o; o.x = a[0]; o.y = a[1]; o.z = a[2]; o.w = a[3];
    *reinterpret_cast<int4*>(cand_key + cb) = o;
    atomicAdd(&row_sum[gRow], rsum[row]);
  } else {
    const int c = tid - 128;
    atomicAdd(&col_sum[tileCol * 128 + c], csum[c]);
  }
}

// ---------------------------------------------------------------------------
// K2: merge 64 per-tile sorted-4 key lists -> global top-4 per row; apply
// alpha corrections (2^{2a} - 2^a) to row_sum (owned) and col_sum (atomic).
// (Separate dispatch from finalize: kernel-boundary coherence is free;
// fused last-block + __threadfence cost 143 us in r11 — never again.)
// ---------------------------------------------------------------------------
__global__ __launch_bounds__(256) void merge_correct(
    const int* __restrict__ cand_key,
    float* __restrict__ row_sum, float* __restrict__ col_sum) {
  const int wave = threadIdx.x >> 6;
  const int lane = threadIdx.x & 63;
  const int row = blockIdx.x * 4 + wave;

  const int4 k4 = *reinterpret_cast<const int4*>(
      cand_key + ((size_t)row << 8) + lane * 4);
  int v[4] = {k4.x, k4.y, k4.z, k4.w};

#pragma unroll
  for (int s = 1; s < 64; s <<= 1) {
    int b[4];
#pragma unroll
    for (int k = 0; k < 4; ++k) b[k] = __shfl_xor(v[k], s);
    merge_top4i(v, b);
  }

  if (lane == 0) {
    float corr = 0.f;
#pragma unroll
    for (int k = 0; k < 4; ++k) {
      const float a = __int_as_float(v[k] & KEY_MASK);
      const float c = EXP2(a + a) - EXP2(a);
      corr += c;
      atomicAdd(&col_sum[v[k] & COL_MASK], c);
    }
    row_sum[row] += corr;   // exclusive owner after K1 completes
  }
}

// ---------------------------------------------------------------------------
// K3: final loss reduction
// ---------------------------------------------------------------------------
__global__ __launch_bounds__(256) void finalize(
    const float* __restrict__ row_sum, const float* __restrict__ col_sum,
    const float* __restrict__ diag, float* __restrict__ out) {
  double s = 0.0;
  for (int i = threadIdx.x; i < B_SIZE; i += 256)
    s += (double)(logf(row_sum[i]) + logf(col_sum[i]) - 2.f * diag[i]);
#pragma unroll
  for (int d = 1; d < 64; d <<= 1) s += __shfl_xor(s, d);
  __shared__ double red[4];
  const int lane = threadIdx.x & 63, wave = threadIdx.x >> 6;
  if (lane == 0) red[wave] = s;
  __syncthreads();
  if (threadIdx.x == 0) {
    const double tot = red[0] + red[1] + red[2] + red[3];
    out[0] = (float)(tot / (2.0 * (double)B_SIZE));
  }
}

// ---------------------------------------------------------------------------
extern "C" void kernel_launch(void* const* d_in, const int* in_sizes, int n_in,
                              void* d_out, int out_size, void* d_ws, size_t ws_size,
                              hipStream_t stream) {
  const float* V = (const float*)d_in[0];
  const float* T = (const float*)d_in[1];
  float* out = (float*)d_out;
  char* ws = (char*)d_ws;

  __hip_bfloat16* Vb = (__hip_bfloat16*)ws;                       // 4 MB
  __hip_bfloat16* Tb = (__hip_bfloat16*)(ws + (4 << 20));         // 4 MB
  float* row_sum = (float*)(ws + (8 << 20));                      // 32 KB
  float* col_sum = row_sum + B_SIZE;                              // 32 KB
  float* diag    = col_sum + B_SIZE;                              // 32 KB
  int*   cand_key = (int*)(ws + (8 << 20) + 3 * B_SIZE * 4);      // 8 MB

  cvt_both<<<4096, 256, 0, stream>>>(V, T, Vb, Tb, row_sum);
  gemm_analyze<<<64 * 64, 256, 0, stream>>>(Vb, Tb, row_sum, col_sum, diag,
                                            cand_key);
  merge_correct<<<B_SIZE / 4, 256, 0, stream>>>(cand_key, row_sum, col_sum);
  finalize<<<1, 256, 0, stream>>>(row_sum, col_sum, diag, out);
}